// Round 1
// baseline (9683.124 us; speedup 1.0000x reference)
//
#include <hip/hip_runtime.h>

// Sizes: T=64, B=64, S=64, E=1024, D=1024, L=2
// Step: x=[emb_t|feed] (2048); gates0 = [x|h0]·Wg0^T (K=3072,N=4096)
//       gates1 = [h_0|h1prev]·Wg1^T (K=2048,N=4096)
//       scores[b,s] = h1·ctx2[b,s,:] with ctx2 = ctx·W_in (precomputed, step-invariant)
//       cvec = softmax(scores)·ctx ; attn_h = tanh([cvec|h1]·W_out^T)

typedef __attribute__((ext_vector_type(8))) short bf16x8;   // 8 bf16 = 4 VGPRs
typedef __attribute__((ext_vector_type(4))) float f32x4;

__device__ __forceinline__ float bf2f(unsigned short u) {
  return __uint_as_float(((unsigned int)u) << 16);
}
__device__ __forceinline__ unsigned short f2bf(float f) {
  unsigned int u = __float_as_uint(f);
  u += 0x7FFFu + ((u >> 16) & 1u);       // round-to-nearest-even
  return (unsigned short)(u >> 16);
}
__device__ __forceinline__ float sigmoidf_(float x) {
  return 1.0f / (1.0f + expf(-x));
}

// ---------------- one-time: pack weights + context to bf16 -----------------
__global__ __launch_bounds__(256) void k_prep(
    const float* __restrict__ Wih0, const float* __restrict__ Whh0,
    const float* __restrict__ Wih1, const float* __restrict__ Whh1,
    const float* __restrict__ Wout, const float* __restrict__ Win,
    const float* __restrict__ ctx,
    unsigned short* __restrict__ Wg0, unsigned short* __restrict__ Wg1,
    unsigned short* __restrict__ Woutb, unsigned short* __restrict__ WinT,
    unsigned short* __restrict__ ctxb)
{
  long i = (long)blockIdx.x * 256 + threadIdx.x;
  const long N0 = 4096L * 3072, N1 = 4096L * 2048, N2 = 1024L * 2048,
             N3 = 1024L * 1024, N4 = 64L * 64 * 1024;
  if (i < N0) {                                   // Wg0 rows: [W_ih0 | W_hh0]
    long j = i / 3072, k = i % 3072;
    float v = (k < 2048) ? Wih0[j * 2048 + k] : Whh0[j * 1024 + (k - 2048)];
    Wg0[i] = f2bf(v);
    return;
  }
  i -= N0;
  if (i < N1) {                                   // Wg1 rows: [W_ih1 | W_hh1]
    long j = i / 2048, k = i % 2048;
    float v = (k < 1024) ? Wih1[j * 1024 + k] : Whh1[j * 1024 + (k - 1024)];
    Wg1[i] = f2bf(v);
    return;
  }
  i -= N1;
  if (i < N2) { Woutb[i] = f2bf(Wout[i]); return; }
  i -= N2;
  if (i < N3) {                                   // W_in transposed [e][d]
    long e = i >> 10, d = i & 1023;
    WinT[i] = f2bf(Win[d * 1024 + e]);
    return;
  }
  i -= N3;
  if (i < N4) { ctxb[i] = f2bf(ctx[i]); }
}

// ---------------- one-time: ctx2[s*64+b][e] = sum_d ctx[s,b,d]*W_in[d,e] ---
__global__ __launch_bounds__(256) void k_ctx2(
    const unsigned short* __restrict__ A,   // ctxb [4096][1024]
    const unsigned short* __restrict__ Bm,  // WinT [1024][1024] (row n, k-contig)
    unsigned short* __restrict__ Cm)        // ctx2 [4096][1024]
{
  const int lane = threadIdx.x & 63;
  const int wv = threadIdx.x >> 6;
  const int quad = lane >> 4;
  const int cL = lane & 15;
  const int n0 = blockIdx.x * 64;
  const int m0 = blockIdx.y * 64 + wv * 16;
  f32x4 a0 = {0,0,0,0}, a1 = {0,0,0,0}, a2 = {0,0,0,0}, a3 = {0,0,0,0};
  const unsigned short* ap  = A  + (size_t)(m0 + cL) * 1024 + quad * 8;
  const unsigned short* bp0 = Bm + (size_t)(n0 +  0 + cL) * 1024 + quad * 8;
  const unsigned short* bp1 = Bm + (size_t)(n0 + 16 + cL) * 1024 + quad * 8;
  const unsigned short* bp2 = Bm + (size_t)(n0 + 32 + cL) * 1024 + quad * 8;
  const unsigned short* bp3 = Bm + (size_t)(n0 + 48 + cL) * 1024 + quad * 8;
  #pragma unroll 4
  for (int kc = 0; kc < 1024; kc += 32) {
    bf16x8 a  = *(const bf16x8*)ap;  ap  += 32;
    bf16x8 b0 = *(const bf16x8*)bp0; bp0 += 32;
    bf16x8 b1 = *(const bf16x8*)bp1; bp1 += 32;
    bf16x8 b2 = *(const bf16x8*)bp2; bp2 += 32;
    bf16x8 b3 = *(const bf16x8*)bp3; bp3 += 32;
    a0 = __builtin_amdgcn_mfma_f32_16x16x32_bf16(a, b0, a0, 0, 0, 0);
    a1 = __builtin_amdgcn_mfma_f32_16x16x32_bf16(a, b1, a1, 0, 0, 0);
    a2 = __builtin_amdgcn_mfma_f32_16x16x32_bf16(a, b2, a2, 0, 0, 0);
    a3 = __builtin_amdgcn_mfma_f32_16x16x32_bf16(a, b3, a3, 0, 0, 0);
  }
  #pragma unroll
  for (int r = 0; r < 4; ++r) {
    size_t base = (size_t)(m0 + quad * 4 + r) * 1024;
    Cm[base + n0 +  0 + cL] = f2bf(a0[r]);
    Cm[base + n0 + 16 + cL] = f2bf(a1[r]);
    Cm[base + n0 + 32 + cL] = f2bf(a2[r]);
    Cm[base + n0 + 48 + cL] = f2bf(a3[r]);
  }
}

// ---------------- one-time: initial state ---------------------------------
__global__ __launch_bounds__(256) void k_init(
    const float* __restrict__ emb0,   // emb[t=0]  [B][E]
    const float* __restrict__ feed0,  // [B][D]
    const float* __restrict__ h0,     // [2][B][D]
    const float* __restrict__ c0,     // [2][B][D]
    unsigned short* __restrict__ x0,  // xbuf0 par0 [64][3072] = [emb|feed|h0_0]
    unsigned short* __restrict__ x1,  // xbuf1 par0 [64][2048] = [h_0|h1prev]
    float* __restrict__ cst)          // c0s (c1s contiguous after)
{
  int i = blockIdx.x * 256 + threadIdx.x;
  if (i < 196608) {
    int b = i / 3072, k = i % 3072;
    float v = (k < 1024) ? emb0[b * 1024 + k]
            : (k < 2048) ? feed0[b * 1024 + (k - 1024)]
                         : h0[b * 1024 + (k - 2048)];
    x0[i] = f2bf(v);
    return;
  }
  i -= 196608;
  if (i < 65536) {
    int b = i >> 10, d = i & 1023;
    x1[b * 2048 + 1024 + d] = f2bf(h0[65536 + b * 1024 + d]);
    return;
  }
  i -= 65536;
  if (i < 131072) cst[i] = c0[i];
}

// ---------------- per step: gates GEMM + fused LSTM pointwise --------------
// grid 64 blocks (16 d-cols each), 4 waves: wave w -> rows 16w..16w+15,
// 4 col-tiles = gates i,f,g,o for d in [d0,d0+16). Lane ends holding all 4
// gates of (b,d) -> pointwise entirely in registers.
__global__ __launch_bounds__(256) void k_lstm(
    const unsigned short* __restrict__ X, int K,
    const unsigned short* __restrict__ Wg,   // [4096][K], row = gate*1024+d
    const float* __restrict__ bih, const float* __restrict__ bhh,
    float* __restrict__ cstate,              // [64][1024] fp32, in-place
    unsigned short* __restrict__ hdst1, int hs1,
    unsigned short* __restrict__ hdst2, int hs2,
    float* __restrict__ hf)                  // optional fp32 h copy (layer 1)
{
  const int lane = threadIdx.x & 63;
  const int wv = threadIdx.x >> 6;
  const int quad = lane >> 4;
  const int cL = lane & 15;
  const int d0 = blockIdx.x * 16;
  const int m0 = wv * 16;

  f32x4 ai = {0,0,0,0}, af = {0,0,0,0}, ag = {0,0,0,0}, ao = {0,0,0,0};
  const unsigned short* ap  = X  + (size_t)(m0 + cL) * K + quad * 8;
  const unsigned short* bpi = Wg + (size_t)(   0 + d0 + cL) * K + quad * 8;
  const unsigned short* bpf = Wg + (size_t)(1024 + d0 + cL) * K + quad * 8;
  const unsigned short* bpg = Wg + (size_t)(2048 + d0 + cL) * K + quad * 8;
  const unsigned short* bpo = Wg + (size_t)(3072 + d0 + cL) * K + quad * 8;
  #pragma unroll 4
  for (int kc = 0; kc < K; kc += 32) {
    bf16x8 a  = *(const bf16x8*)ap;  ap  += 32;
    bf16x8 bi = *(const bf16x8*)bpi; bpi += 32;
    bf16x8 bf = *(const bf16x8*)bpf; bpf += 32;
    bf16x8 bg = *(const bf16x8*)bpg; bpg += 32;
    bf16x8 bo = *(const bf16x8*)bpo; bpo += 32;
    ai = __builtin_amdgcn_mfma_f32_16x16x32_bf16(a, bi, ai, 0, 0, 0);
    af = __builtin_amdgcn_mfma_f32_16x16x32_bf16(a, bf, af, 0, 0, 0);
    ag = __builtin_amdgcn_mfma_f32_16x16x32_bf16(a, bg, ag, 0, 0, 0);
    ao = __builtin_amdgcn_mfma_f32_16x16x32_bf16(a, bo, ao, 0, 0, 0);
  }
  const int d = d0 + cL;
  const float bias_i = bih[   0 + d] + bhh[   0 + d];
  const float bias_f = bih[1024 + d] + bhh[1024 + d];
  const float bias_g = bih[2048 + d] + bhh[2048 + d];
  const float bias_o = bih[3072 + d] + bhh[3072 + d];
  #pragma unroll
  for (int r = 0; r < 4; ++r) {
    const int b = m0 + quad * 4 + r;
    const float iv = ai[r] + bias_i;
    const float fv = af[r] + bias_f;
    const float gv = ag[r] + bias_g;
    const float ov = ao[r] + bias_o;
    const size_t ci = (size_t)b * 1024 + d;
    const float c_old = cstate[ci];
    const float c_new = sigmoidf_(fv) * c_old + sigmoidf_(iv) * tanhf(gv);
    const float h = sigmoidf_(ov) * tanhf(c_new);
    cstate[ci] = c_new;
    const unsigned short hb = f2bf(h);
    hdst1[(size_t)b * hs1 + d] = hb;
    hdst2[(size_t)b * hs2 + d] = hb;
    if (hf) hf[ci] = h;
  }
}

// ---------------- per step: scores + softmax + cvec (one block per b) ------
__global__ __launch_bounds__(256) void k_attn(
    const float* __restrict__ h1f,          // [64][1024] fp32
    const unsigned short* __restrict__ ctx2,// [S*B][1024] bf16
    const unsigned short* __restrict__ ctxb,// [S*B][1024] bf16
    unsigned short* __restrict__ cvec,      // [64][1024] bf16
    float* __restrict__ attnOut)            // d_out attns slice [B][S]
{
  const int b = blockIdx.x;
  const int tid = threadIdx.x;
  __shared__ float h1s[1024];
  __shared__ float red[64][4];
  __shared__ float al[64];
  for (int i = tid; i < 1024; i += 256) h1s[i] = h1f[(size_t)b * 1024 + i];
  __syncthreads();
  {
    const int s = tid >> 2, p = tid & 3;
    const unsigned short* crow = ctx2 + (size_t)(s * 64 + b) * 1024 + p * 256;
    const float* hp = h1s + p * 256;
    float part = 0.f;
    #pragma unroll 4
    for (int e = 0; e < 256; e += 4) {
      ushort4 cc = *(const ushort4*)(crow + e);
      part += hp[e + 0] * bf2f(cc.x) + hp[e + 1] * bf2f(cc.y)
            + hp[e + 2] * bf2f(cc.z) + hp[e + 3] * bf2f(cc.w);
    }
    red[s][p] = part;
  }
  __syncthreads();
  if (tid < 64) {   // wave 0: softmax over S=64
    float sc = red[tid][0] + red[tid][1] + red[tid][2] + red[tid][3];
    float mx = sc;
    for (int off = 32; off > 0; off >>= 1) mx = fmaxf(mx, __shfl_xor(mx, off, 64));
    const float ex = expf(sc - mx);
    float sm = ex;
    for (int off = 32; off > 0; off >>= 1) sm += __shfl_xor(sm, off, 64);
    const float a = ex / sm;
    al[tid] = a;
    attnOut[(size_t)b * 64 + tid] = a;
  }
  __syncthreads();
  {
    float v0 = 0, v1 = 0, v2 = 0, v3 = 0;
    const int e0 = tid * 4;
    for (int s = 0; s < 64; ++s) {
      const float a = al[s];
      ushort4 cc = *(const ushort4*)(ctxb + (size_t)(s * 64 + b) * 1024 + e0);
      v0 += a * bf2f(cc.x); v1 += a * bf2f(cc.y);
      v2 += a * bf2f(cc.z); v3 += a * bf2f(cc.w);
    }
    unsigned short* cp = cvec + (size_t)b * 1024 + e0;
    cp[0] = f2bf(v0); cp[1] = f2bf(v1); cp[2] = f2bf(v2); cp[3] = f2bf(v3);
  }
}

// ---------------- per step: attn_h = tanh([cvec|h1]·Wout^T) ---------------
// Also stages feed + next emb into xbuf0[next parity].
__global__ __launch_bounds__(256) void k_attnout(
    const unsigned short* __restrict__ cvec,  // [64][1024]
    const unsigned short* __restrict__ h1,    // [64][1024]
    const unsigned short* __restrict__ Wo,    // [1024][2048]
    float* __restrict__ outT,                 // d_out outputs slice [B][D]
    unsigned short* __restrict__ xnext,       // xbuf0 next [64][3072]
    const float* __restrict__ embNext)        // emb[t+1] or null
{
  const int lane = threadIdx.x & 63;
  const int wv = threadIdx.x >> 6;
  const int quad = lane >> 4;
  const int cL = lane & 15;
  const int n0 = blockIdx.x * 64;
  const int m0 = wv * 16;
  f32x4 a0 = {0,0,0,0}, a1 = {0,0,0,0}, a2 = {0,0,0,0}, a3 = {0,0,0,0};
  #pragma unroll
  for (int half = 0; half < 2; ++half) {
    const unsigned short* A = half ? h1 : cvec;
    const unsigned short* ap  = A  + (size_t)(m0 + cL) * 1024 + quad * 8;
    const unsigned short* bp0 = Wo + (size_t)(n0 +  0 + cL) * 2048 + half * 1024 + quad * 8;
    const unsigned short* bp1 = Wo + (size_t)(n0 + 16 + cL) * 2048 + half * 1024 + quad * 8;
    const unsigned short* bp2 = Wo + (size_t)(n0 + 32 + cL) * 2048 + half * 1024 + quad * 8;
    const unsigned short* bp3 = Wo + (size_t)(n0 + 48 + cL) * 2048 + half * 1024 + quad * 8;
    #pragma unroll 4
    for (int kc = 0; kc < 1024; kc += 32) {
      bf16x8 a  = *(const bf16x8*)ap;  ap  += 32;
      bf16x8 b0 = *(const bf16x8*)bp0; bp0 += 32;
      bf16x8 b1 = *(const bf16x8*)bp1; bp1 += 32;
      bf16x8 b2 = *(const bf16x8*)bp2; bp2 += 32;
      bf16x8 b3 = *(const bf16x8*)bp3; bp3 += 32;
      a0 = __builtin_amdgcn_mfma_f32_16x16x32_bf16(a, b0, a0, 0, 0, 0);
      a1 = __builtin_amdgcn_mfma_f32_16x16x32_bf16(a, b1, a1, 0, 0, 0);
      a2 = __builtin_amdgcn_mfma_f32_16x16x32_bf16(a, b2, a2, 0, 0, 0);
      a3 = __builtin_amdgcn_mfma_f32_16x16x32_bf16(a, b3, a3, 0, 0, 0);
    }
  }
  #pragma unroll
  for (int r = 0; r < 4; ++r) {
    const int b = m0 + quad * 4 + r;
    float v;
    v = tanhf(a0[r]); outT[(size_t)b * 1024 + n0 +  0 + cL] = v;
    xnext[(size_t)b * 3072 + 1024 + n0 +  0 + cL] = f2bf(v);
    v = tanhf(a1[r]); outT[(size_t)b * 1024 + n0 + 16 + cL] = v;
    xnext[(size_t)b * 3072 + 1024 + n0 + 16 + cL] = f2bf(v);
    v = tanhf(a2[r]); outT[(size_t)b * 1024 + n0 + 32 + cL] = v;
    xnext[(size_t)b * 3072 + 1024 + n0 + 32 + cL] = f2bf(v);
    v = tanhf(a3[r]); outT[(size_t)b * 1024 + n0 + 48 + cL] = v;
    xnext[(size_t)b * 3072 + 1024 + n0 + 48 + cL] = f2bf(v);
  }
  if (embNext) {  // stage next step's emb slice (this block's 64 columns)
    #pragma unroll
    for (int it = 0; it < 16; ++it) {
      const int idx = it * 256 + threadIdx.x;
      const int bb = idx >> 6;
      const int col = n0 + (idx & 63);
      xnext[(size_t)bb * 3072 + col] = f2bf(embNext[(size_t)bb * 1024 + col]);
    }
  }
}

extern "C" void kernel_launch(void* const* d_in, const int* in_sizes, int n_in,
                              void* d_out, int out_size, void* d_ws, size_t ws_size,
                              hipStream_t stream)
{
  const float* emb   = (const float*)d_in[0];
  const float* ctx   = (const float*)d_in[1];
  const float* feed0 = (const float*)d_in[2];
  const float* h0    = (const float*)d_in[3];
  const float* c0    = (const float*)d_in[4];
  const float* Wih0  = (const float*)d_in[5];
  const float* Whh0  = (const float*)d_in[6];
  const float* bih0  = (const float*)d_in[7];
  const float* bhh0  = (const float*)d_in[8];
  const float* Wih1  = (const float*)d_in[9];
  const float* Whh1  = (const float*)d_in[10];
  const float* bih1  = (const float*)d_in[11];
  const float* bhh1  = (const float*)d_in[12];
  const float* Win   = (const float*)d_in[13];
  const float* WoutW = (const float*)d_in[14];
  float* out = (float*)d_out;

  char* w = (char*)d_ws;
  unsigned short* Wg0   = (unsigned short*)(w);             // [4096][3072] bf16
  unsigned short* Wg1   = (unsigned short*)(w + 25165824);  // [4096][2048]
  unsigned short* Woutb = (unsigned short*)(w + 41943040);  // [1024][2048]
  unsigned short* WinT  = (unsigned short*)(w + 46137344);  // [1024][1024]
  unsigned short* ctxb  = (unsigned short*)(w + 48234496);  // [4096][1024]
  unsigned short* ctx2  = (unsigned short*)(w + 56623104);  // [4096][1024]
  unsigned short* xbuf0 = (unsigned short*)(w + 65011712);  // 2x[64][3072]
  unsigned short* xbuf1 = (unsigned short*)(w + 65798144);  // 2x[64][2048]
  unsigned short* h1cur = (unsigned short*)(w + 66322432);  // [64][1024]
  unsigned short* cvec  = (unsigned short*)(w + 66453504);  // [64][1024]
  float*          c0s   = (float*)(w + 66584576);           // [64][1024] f32
  float*          c1s   = (float*)(w + 66846720);           // [64][1024] f32
  float*          h1f   = (float*)(w + 67108864);           // [64][1024] f32

  k_prep<<<110592, 256, 0, stream>>>(Wih0, Whh0, Wih1, Whh1, WoutW, Win, ctx,
                                     Wg0, Wg1, Woutb, WinT, ctxb);
  k_ctx2<<<dim3(16, 64), 256, 0, stream>>>(ctxb, WinT, ctx2);
  k_init<<<1536, 256, 0, stream>>>(emb, feed0, h0, c0, xbuf0, xbuf1, c0s);

  float* outA = out + 4194304;   // attns region [T][B][S]
  for (int t = 0; t < 64; ++t) {
    const int par = t & 1;
    unsigned short* x0  = xbuf0 + (size_t)par * 196608;
    unsigned short* x0n = xbuf0 + (size_t)(1 - par) * 196608;
    unsigned short* x1  = xbuf1 + (size_t)par * 131072;
    unsigned short* x1n = xbuf1 + (size_t)(1 - par) * 131072;
    // layer 0: writes h_0 -> xbuf1[par][:,0:1024] and xbuf0[next][:,2048:3072]
    k_lstm<<<64, 256, 0, stream>>>(x0, 3072, Wg0, bih0, bhh0, c0s,
                                   x1, 2048, x0n + 2048, 3072, (float*)nullptr);
    // layer 1: writes h_1 -> xbuf1[next][:,1024:2048], h1cur, h1f
    k_lstm<<<64, 256, 0, stream>>>(x1, 2048, Wg1, bih1, bhh1, c1s,
                                   x1n + 1024, 2048, h1cur, 1024, h1f);
    k_attn<<<64, 256, 0, stream>>>(h1f, ctx2, ctxb, cvec, outA + (size_t)t * 4096);
    k_attnout<<<16, 256, 0, stream>>>(cvec, h1cur, Woutb, out + (size_t)t * 65536,
                                      x0n, (t < 63) ? (emb + (size_t)(t + 1) * 65536)
                                                    : (const float*)nullptr);
  }
}

// Round 2
// 8196.144 us; speedup vs baseline: 1.1814x; 1.1814x over previous
//
#include <hip/hip_runtime.h>

// T=64, B=64, S=64, E=1024, D=1024, L=2
// Persistent-kernel schedule per step t (4 device-wide barriers):
//   A : gates0 = xA[p]([attn_h|emb_t|h0prev], K=3072)·Wg0p^T + b0sum -> pointwise -> h_0
//   B : gates1 = xB1[p]([h_0|h1prev], K=2048)·Wg1p^T + b1sum -> pointwise -> h1
//   C': scores = h1f·ctx2 (per-b), softmax -> align ; qh = h1·WoutH^T (concurrent blocks)
//   D': attn_h = tanh(qh + sum_s align*ctx3[s,b,:]) ; stage xA[1-p] (+ next emb)
// with ctx2 = ctx·W_in (scores hoist), ctx3 = Wout[:, :1024]·ctx (output-GEMM hoist).

typedef __attribute__((ext_vector_type(8))) short bf16x8;
typedef __attribute__((ext_vector_type(4))) float f32x4;
typedef unsigned short u16;

__device__ __forceinline__ float bf2f(u16 u) {
  return __uint_as_float(((unsigned int)u) << 16);
}
__device__ __forceinline__ u16 f2bf(float f) {
  unsigned int u = __float_as_uint(f);
  u += 0x7FFFu + ((u >> 16) & 1u);
  return (u16)(u >> 16);
}
__device__ __forceinline__ float sigmoidf_(float x) { return 1.0f / (1.0f + expf(-x)); }

// ---------------- one-time: pack weights/context to bf16, bias sums --------
__global__ __launch_bounds__(256) void k_prep(
    const float* __restrict__ Wih0, const float* __restrict__ Whh0,
    const float* __restrict__ Wih1, const float* __restrict__ Whh1,
    const float* __restrict__ Wout, const float* __restrict__ Win,
    const float* __restrict__ ctx,
    const float* __restrict__ bih0, const float* __restrict__ bhh0,
    const float* __restrict__ bih1, const float* __restrict__ bhh1,
    u16* __restrict__ Wg0p, u16* __restrict__ Wg1p,
    u16* __restrict__ WoutCb, u16* __restrict__ WoutHb,
    u16* __restrict__ WinT, u16* __restrict__ ctxb,
    float* __restrict__ b0sum, float* __restrict__ b1sum)
{
  long i = (long)blockIdx.x * 256 + threadIdx.x;
  const long N0 = 4096L * 3072, N1 = 4096L * 2048, NM = 1024L * 1024,
             NC = 4194304L;
  if (i < N0) {  // Wg0p rows gd: [Wih0_feed | Wih0_emb | Whh0]
    long j = i / 3072, k = i % 3072;
    float v = (k < 1024) ? Wih0[j * 2048 + 1024 + k]
            : (k < 2048) ? Wih0[j * 2048 + (k - 1024)]
                         : Whh0[j * 1024 + (k - 2048)];
    Wg0p[i] = f2bf(v); return;
  }
  i -= N0;
  if (i < N1) {  // Wg1p rows gd: [Wih1 | Whh1]
    long j = i / 2048, k = i % 2048;
    float v = (k < 1024) ? Wih1[j * 1024 + k] : Whh1[j * 1024 + (k - 1024)];
    Wg1p[i] = f2bf(v); return;
  }
  i -= N1;
  if (i < NM) { long d = i >> 10, e = i & 1023; WoutCb[i] = f2bf(Wout[d * 2048 + e]); return; }
  i -= NM;
  if (i < NM) { long d = i >> 10, e = i & 1023; WoutHb[i] = f2bf(Wout[d * 2048 + 1024 + e]); return; }
  i -= NM;
  if (i < NM) { long e = i >> 10, d = i & 1023; WinT[i] = f2bf(Win[d * 1024 + e]); return; }
  i -= NM;
  if (i < NC) { ctxb[i] = f2bf(ctx[i]); return; }
  i -= NC;
  if (i < 4096) { b0sum[i] = bih0[i] + bhh0[i]; return; }
  i -= 4096;
  if (i < 4096) { b1sum[i] = bih1[i] + bhh1[i]; }
}

// ---------------- one-time: C[m][n] = sum_k A[m][k]*B[n][k], M=4096,N=1024,K=1024
__global__ __launch_bounds__(256) void k_gemm1k(
    const u16* __restrict__ A, const u16* __restrict__ Bm, u16* __restrict__ Cm)
{
  const int lane = threadIdx.x & 63, wv = threadIdx.x >> 6;
  const int quad = lane >> 4, cL = lane & 15;
  const int n0 = blockIdx.x * 64;
  const int m0 = blockIdx.y * 64 + wv * 16;
  f32x4 a0 = {0,0,0,0}, a1 = {0,0,0,0}, a2 = {0,0,0,0}, a3 = {0,0,0,0};
  const u16* ap  = A  + (size_t)(m0 + cL) * 1024 + quad * 8;
  const u16* bp0 = Bm + (size_t)(n0 +  0 + cL) * 1024 + quad * 8;
  const u16* bp1 = Bm + (size_t)(n0 + 16 + cL) * 1024 + quad * 8;
  const u16* bp2 = Bm + (size_t)(n0 + 32 + cL) * 1024 + quad * 8;
  const u16* bp3 = Bm + (size_t)(n0 + 48 + cL) * 1024 + quad * 8;
  #pragma unroll 4
  for (int kc = 0; kc < 1024; kc += 32) {
    bf16x8 a  = *(const bf16x8*)ap;  ap  += 32;
    bf16x8 b0 = *(const bf16x8*)bp0; bp0 += 32;
    bf16x8 b1 = *(const bf16x8*)bp1; bp1 += 32;
    bf16x8 b2 = *(const bf16x8*)bp2; bp2 += 32;
    bf16x8 b3 = *(const bf16x8*)bp3; bp3 += 32;
    a0 = __builtin_amdgcn_mfma_f32_16x16x32_bf16(a, b0, a0, 0, 0, 0);
    a1 = __builtin_amdgcn_mfma_f32_16x16x32_bf16(a, b1, a1, 0, 0, 0);
    a2 = __builtin_amdgcn_mfma_f32_16x16x32_bf16(a, b2, a2, 0, 0, 0);
    a3 = __builtin_amdgcn_mfma_f32_16x16x32_bf16(a, b3, a3, 0, 0, 0);
  }
  #pragma unroll
  for (int r = 0; r < 4; ++r) {
    size_t base = (size_t)(m0 + quad * 4 + r) * 1024;
    Cm[base + n0 +  0 + cL] = f2bf(a0[r]);
    Cm[base + n0 + 16 + cL] = f2bf(a1[r]);
    Cm[base + n0 + 32 + cL] = f2bf(a2[r]);
    Cm[base + n0 + 48 + cL] = f2bf(a3[r]);
  }
}

// ---------------- one-time: initial state + barrier reset ------------------
__global__ __launch_bounds__(256) void k_init(
    const float* __restrict__ emb, const float* __restrict__ feed0,
    const float* __restrict__ h0, const float* __restrict__ c0,
    u16* __restrict__ xA, u16* __restrict__ xB1, float* __restrict__ cst,
    unsigned int* __restrict__ bar)
{
  int i = blockIdx.x * 256 + threadIdx.x;
  if (i < 196608) {  // xA[par0] = [feed | emb_0 | h0_layer0]
    int b = i / 3072, k = i % 3072;
    float v = (k < 1024) ? feed0[b * 1024 + k]
            : (k < 2048) ? emb[b * 1024 + (k - 1024)]
                         : h0[b * 1024 + (k - 2048)];
    xA[i] = f2bf(v); return;
  }
  i -= 196608;
  if (i < 65536) {  // xB1[par0][:,1024:] = h0_layer1
    int b = i >> 10, d = i & 1023;
    xB1[b * 2048 + 1024 + d] = f2bf(h0[65536 + b * 1024 + d]); return;
  }
  i -= 65536;
  if (i < 131072) { cst[i] = c0[i]; return; }   // c0s,c1s contiguous
  i -= 131072;
  if (i < 64) bar[i] = 0;
}

// ---------------- device-wide barrier (sense via generation counter) -------
__device__ __forceinline__ void grid_barrier(unsigned int* bar, unsigned int gen) {
  __syncthreads();
  if (threadIdx.x == 0) {
    __threadfence();   // agent-scope release of this block's writes
    unsigned int prev = __hip_atomic_fetch_add(&bar[0], 1u, __ATOMIC_RELAXED,
                                               __HIP_MEMORY_SCOPE_AGENT);
    if (prev == gridDim.x - 1) {
      __hip_atomic_store(&bar[0], 0u, __ATOMIC_RELAXED, __HIP_MEMORY_SCOPE_AGENT);
      __threadfence();
      __hip_atomic_store(&bar[16], gen, __ATOMIC_RELEASE, __HIP_MEMORY_SCOPE_AGENT);
    } else {
      while (__hip_atomic_load(&bar[16], __ATOMIC_RELAXED,
                               __HIP_MEMORY_SCOPE_AGENT) < gen)
        __builtin_amdgcn_s_sleep(2);
    }
    __threadfence();   // acquire side
  }
  __syncthreads();
}

// ---------------- LSTM phase tile: block=(rg,dg), wave=gate ----------------
__device__ __forceinline__ void lstm_tile(
    const u16* __restrict__ X, int K, const u16* __restrict__ W,
    const float* __restrict__ bsum, float* __restrict__ cst,
    u16* __restrict__ hA, int hAs, int hAoff,
    u16* __restrict__ hB, int hBs, int hBoff,
    float* __restrict__ hf, int bi, int tid, float* smem)
{
  const int w = tid >> 6, lane = tid & 63, quad = lane >> 4, cL = lane & 15;
  const int rg = bi & 3, dg = bi >> 2;
  const u16* ap = X + (size_t)(rg * 16 + cL) * K + quad * 8;
  const u16* bp = W + (size_t)(w * 1024 + dg * 16 + cL) * K + quad * 8;
  f32x4 a0 = {0,0,0,0}, a1 = {0,0,0,0};
  #pragma unroll 4
  for (int kc = 0; kc < K; kc += 64) {
    bf16x8 av0 = *(const bf16x8*)ap;
    bf16x8 bv0 = *(const bf16x8*)bp;
    bf16x8 av1 = *(const bf16x8*)(ap + 32);
    bf16x8 bv1 = *(const bf16x8*)(bp + 32);
    ap += 64; bp += 64;
    a0 = __builtin_amdgcn_mfma_f32_16x16x32_bf16(av0, bv0, a0, 0, 0, 0);
    a1 = __builtin_amdgcn_mfma_f32_16x16x32_bf16(av1, bv1, a1, 0, 0, 0);
  }
  #pragma unroll
  for (int r = 0; r < 4; ++r)
    smem[w * 256 + (quad * 4 + r) * 16 + cL] = a0[r] + a1[r];
  __syncthreads();
  const int r = tid >> 4, c = tid & 15;
  const int b = rg * 16 + r, d = dg * 16 + c;
  const float gi = smem[0 * 256 + r * 16 + c] + bsum[d];
  const float gf = smem[1 * 256 + r * 16 + c] + bsum[1024 + d];
  const float gg = smem[2 * 256 + r * 16 + c] + bsum[2048 + d];
  const float go = smem[3 * 256 + r * 16 + c] + bsum[3072 + d];
  const size_t ci = (size_t)b * 1024 + d;
  const float cn = sigmoidf_(gf) * cst[ci] + sigmoidf_(gi) * tanhf(gg);
  const float h  = sigmoidf_(go) * tanhf(cn);
  cst[ci] = cn;
  const u16 hb = f2bf(h);
  hA[(size_t)b * hAs + hAoff + d] = hb;
  if (hB) hB[(size_t)b * hBs + hBoff + d] = hb;
  if (hf) hf[ci] = h;
}

// ---------------- C' part 1: scores + softmax for one b --------------------
__device__ __forceinline__ void scores_softmax(
    int b, const float* __restrict__ h1f, const u16* __restrict__ ctx2,
    float* __restrict__ alignG, float* __restrict__ attnOut, int tid, float* smem)
{
  float* h1s = smem;          // [1024]
  float* red = smem + 1024;   // [256]
  for (int i = tid; i < 1024; i += 256) h1s[i] = h1f[(size_t)b * 1024 + i];
  __syncthreads();
  {
    const int s = tid >> 2, pq = tid & 3;
    const u16* crow = ctx2 + (size_t)(s * 64 + b) * 1024 + pq * 256;
    const float* hp = h1s + pq * 256;
    float part = 0.f;
    #pragma unroll 8
    for (int e = 0; e < 256; e += 4) {
      ushort4 cc = *(const ushort4*)(crow + e);
      part += hp[e] * bf2f(cc.x) + hp[e + 1] * bf2f(cc.y)
            + hp[e + 2] * bf2f(cc.z) + hp[e + 3] * bf2f(cc.w);
    }
    red[tid] = part;
  }
  __syncthreads();
  if (tid < 64) {
    float sc = red[tid * 4] + red[tid * 4 + 1] + red[tid * 4 + 2] + red[tid * 4 + 3];
    float mx = sc;
    for (int off = 32; off; off >>= 1) mx = fmaxf(mx, __shfl_xor(mx, off, 64));
    const float ex = expf(sc - mx);
    float sm = ex;
    for (int off = 32; off; off >>= 1) sm += __shfl_xor(sm, off, 64);
    const float a = ex / sm;
    alignG[b * 64 + tid] = a;
    attnOut[b * 64 + tid] = a;
  }
}

// ---------------- C' part 2: qh = h1 · WoutH^T (one 16-col group) ----------
__device__ __forceinline__ void qh_gemm(
    int cg, const u16* __restrict__ h1, const u16* __restrict__ WH,
    float* __restrict__ qh, int tid)
{
  const int w = tid >> 6, lane = tid & 63, quad = lane >> 4, cL = lane & 15;
  const u16* ap = h1 + (size_t)(w * 16 + cL) * 2048 + quad * 8;
  const u16* bp = WH + (size_t)(cg * 16 + cL) * 1024 + quad * 8;
  f32x4 a0 = {0,0,0,0}, a1 = {0,0,0,0};
  #pragma unroll 4
  for (int kc = 0; kc < 1024; kc += 64) {
    bf16x8 av0 = *(const bf16x8*)ap;
    bf16x8 bv0 = *(const bf16x8*)bp;
    bf16x8 av1 = *(const bf16x8*)(ap + 32);
    bf16x8 bv1 = *(const bf16x8*)(bp + 32);
    ap += 64; bp += 64;
    a0 = __builtin_amdgcn_mfma_f32_16x16x32_bf16(av0, bv0, a0, 0, 0, 0);
    a1 = __builtin_amdgcn_mfma_f32_16x16x32_bf16(av1, bv1, a1, 0, 0, 0);
  }
  #pragma unroll
  for (int r = 0; r < 4; ++r)
    qh[(size_t)(w * 16 + quad * 4 + r) * 1024 + cg * 16 + cL] = a0[r] + a1[r];
}

// ---------------- D': attn_h = tanh(qh + sum_s align*ctx3) -----------------
__device__ __forceinline__ void dprime(
    int bi, int tid, const float* __restrict__ qh, const float* __restrict__ alignG,
    const u16* __restrict__ ctx3, float* __restrict__ outT, u16* __restrict__ xAn,
    const float* __restrict__ embNext, float* smem)
{
  const int b = bi >> 2, dc = bi & 3;
  const int d = dc * 256 + tid;
  if (tid < 64) smem[tid] = alignG[b * 64 + tid];
  __syncthreads();
  float acc = qh[(size_t)b * 1024 + d];
  const u16* cp = ctx3 + (size_t)b * 1024 + d;
  #pragma unroll 8
  for (int s = 0; s < 64; ++s)
    acc += smem[s] * bf2f(cp[(size_t)s * 65536]);
  const float v = tanhf(acc);
  outT[(size_t)b * 1024 + d] = v;
  xAn[(size_t)b * 3072 + d] = f2bf(v);
  if (embNext) xAn[(size_t)b * 3072 + 1024 + d] = f2bf(embNext[(size_t)b * 1024 + d]);
}

// ---------------- the persistent kernel ------------------------------------
__global__ __launch_bounds__(256, 1) void k_persist(
    const u16* __restrict__ Wg0p, const u16* __restrict__ Wg1p,
    const u16* __restrict__ WoutHb, const u16* __restrict__ ctx2,
    const u16* __restrict__ ctx3, const float* __restrict__ b0sum,
    const float* __restrict__ b1sum, const float* __restrict__ emb,
    u16* __restrict__ xA, u16* __restrict__ xB1, float* __restrict__ h1f,
    float* __restrict__ c0s, float* __restrict__ c1s, float* __restrict__ qh,
    float* __restrict__ alignG, unsigned int* __restrict__ bar,
    float* __restrict__ out, float* __restrict__ outA)
{
  const int bi = blockIdx.x, tid = threadIdx.x;
  __shared__ float smem[1280];
  unsigned int gen = 0;
  for (int t = 0; t < 64; ++t) {
    const int p = t & 1;
    u16* xAp = xA + (size_t)p * 196608;
    u16* xAn = xA + (size_t)(1 - p) * 196608;
    u16* xBp = xB1 + (size_t)p * 131072;
    u16* xBn = xB1 + (size_t)(1 - p) * 131072;
    // A: lstm0  (h_0 -> xB1[p][:, :1024]  and  xA[1-p][:, 2048:])
    lstm_tile(xAp, 3072, Wg0p, b0sum, c0s,
              xBp, 2048, 0, xAn, 3072, 2048, nullptr, bi, tid, smem);
    grid_barrier(bar, ++gen);
    // B: lstm1  (h1 -> xB1[1-p][:, 1024:]  and  h1f fp32)
    lstm_tile(xBp, 2048, Wg1p, b1sum, c1s,
              xBn, 2048, 1024, (u16*)nullptr, 0, 0, h1f, bi, tid, smem);
    grid_barrier(bar, ++gen);
    // C': scores+softmax (blocks 0-63) | qh GEMM (blocks 64-127)
    if (bi < 64)
      scores_softmax(bi, h1f, ctx2, alignG, outA + (size_t)t * 4096, tid, smem);
    else if (bi < 128)
      qh_gemm(bi - 64, xBn + 1024, WoutHb, qh, tid);
    grid_barrier(bar, ++gen);
    // D': attn_h + stage next x
    dprime(bi, tid, qh, alignG, ctx3, out + (size_t)t * 65536, xAn,
           (t < 63) ? (emb + (size_t)(t + 1) * 65536) : (const float*)nullptr, smem);
    grid_barrier(bar, ++gen);
  }
}

extern "C" void kernel_launch(void* const* d_in, const int* in_sizes, int n_in,
                              void* d_out, int out_size, void* d_ws, size_t ws_size,
                              hipStream_t stream)
{
  const float* emb   = (const float*)d_in[0];
  const float* ctx   = (const float*)d_in[1];
  const float* feed0 = (const float*)d_in[2];
  const float* h0    = (const float*)d_in[3];
  const float* c0    = (const float*)d_in[4];
  const float* Wih0  = (const float*)d_in[5];
  const float* Whh0  = (const float*)d_in[6];
  const float* bih0  = (const float*)d_in[7];
  const float* bhh0  = (const float*)d_in[8];
  const float* Wih1  = (const float*)d_in[9];
  const float* Whh1  = (const float*)d_in[10];
  const float* bih1  = (const float*)d_in[11];
  const float* bhh1  = (const float*)d_in[12];
  const float* Win   = (const float*)d_in[13];
  const float* WoutW = (const float*)d_in[14];
  float* out = (float*)d_out;

  char* w = (char*)d_ws;
  u16*   Wg0p   = (u16*)(w + 0);            // 4096x3072 bf16
  u16*   Wg1p   = (u16*)(w + 25165824);     // 4096x2048
  u16*   WoutCb = (u16*)(w + 41943040);     // 1024x1024
  u16*   WoutHb = (u16*)(w + 44040192);     // 1024x1024
  u16*   WinT   = (u16*)(w + 46137344);     // 1024x1024
  u16*   ctxb   = (u16*)(w + 48234496);     // 4096x1024
  u16*   ctx2   = (u16*)(w + 56623104);     // 4096x1024
  u16*   ctx3   = (u16*)(w + 65011712);     // 4096x1024
  u16*   xA     = (u16*)(w + 73400320);     // 2 x 64x3072
  u16*   xB1    = (u16*)(w + 74186752);     // 2 x 64x2048
  float* h1f    = (float*)(w + 74711040);   // 64x1024
  float* c0s    = (float*)(w + 74973184);   // 64x1024
  float* c1s    = (float*)(w + 75235328);   // 64x1024 (contiguous after c0s)
  float* qh     = (float*)(w + 75497472);   // 64x1024
  float* alignG = (float*)(w + 75759616);   // 64x64
  float* b0sum  = (float*)(w + 75776000);   // 4096
  float* b1sum  = (float*)(w + 75792384);   // 4096
  unsigned int* bar = (unsigned int*)(w + 75808768);  // barrier words

  k_prep<<<110624, 256, 0, stream>>>(Wih0, Whh0, Wih1, Whh1, WoutW, Win, ctx,
                                     bih0, bhh0, bih1, bhh1,
                                     Wg0p, Wg1p, WoutCb, WoutHb, WinT, ctxb,
                                     b0sum, b1sum);
  k_gemm1k<<<dim3(16, 64), 256, 0, stream>>>(ctxb, WinT, ctx2);
  k_gemm1k<<<dim3(16, 64), 256, 0, stream>>>(ctxb, WoutCb, ctx3);
  k_init<<<1537, 256, 0, stream>>>(emb, feed0, h0, c0, xA, xB1, c0s, bar);

  k_persist<<<256, 256, 0, stream>>>(Wg0p, Wg1p, WoutHb, ctx2, ctx3,
                                     b0sum, b1sum, emb,
                                     xA, xB1, h1f, c0s, c1s, qh, alignG, bar,
                                     out, out + 4194304);
}